// Round 1
// baseline (693.773 us; speedup 1.0000x reference)
//
#include <hip/hip_runtime.h>
#include <math.h>

#define HH 128
#define WW 128
#define HWSZ (HH * WW)
#define BB 2
#define COUT 128

// ---------------------------------------------------------------------------
// Transpose main-conv weights: w (Cout, K) -> wT (K, Cout), K = Cin*9
// ---------------------------------------------------------------------------
__global__ __launch_bounds__(256) void wtrans_kernel(const float* __restrict__ w,
                                                     float* __restrict__ wT, int K) {
  int t = blockIdx.x * 256 + threadIdx.x;
  if (t >= K * COUT) return;
  int o = t & (COUT - 1);
  int k = t >> 7;
  wT[(size_t)k * COUT + o] = w[(size_t)o * K + k];
}

// ---------------------------------------------------------------------------
// Offset conv: off(b, 18, y, x) = conv3x3(in, offw, pad 1) + offb
// thread = (b, half, y, x); computes 9 output channels (j = half*9 + jj)
// Weight addresses are wave-uniform (y/half/b uniform across the 64-lane wave)
// ---------------------------------------------------------------------------
__global__ __launch_bounds__(256) void offconv_kernel(const float* __restrict__ in,
                                                      const float* __restrict__ offw,
                                                      const float* __restrict__ offb,
                                                      float* __restrict__ off, int Cin) {
  int t = blockIdx.x * 256 + threadIdx.x;  // total BB*2*HH*WW = 65536
  int xi = t & 127;
  int y = (t >> 7) & 127;
  int half = (t >> 14) & 1;
  int b = t >> 15;

  float acc[9];
#pragma unroll
  for (int j = 0; j < 9; j++) acc[j] = 0.f;

  for (int c = 0; c < Cin; c++) {
    const float* plane = in + (size_t)(b * Cin + c) * HWSZ;
    float tap[9];
#pragma unroll
    for (int ky = 0; ky < 3; ky++) {
      int yy = y - 1 + ky;
      bool vy = (unsigned)yy < (unsigned)HH;
#pragma unroll
      for (int kx = 0; kx < 3; kx++) {
        int xx = xi - 1 + kx;
        bool ok = vy && ((unsigned)xx < (unsigned)WW);
        tap[ky * 3 + kx] = ok ? plane[yy * WW + xx] : 0.f;
      }
    }
    const float* wp = offw + ((size_t)(half * 9) * Cin + c) * 9;
#pragma unroll
    for (int j = 0; j < 9; j++) {
      const float* wq = wp + (size_t)j * Cin * 9;
      acc[j] += tap[0] * wq[0] + tap[1] * wq[1] + tap[2] * wq[2]
              + tap[3] * wq[3] + tap[4] * wq[4] + tap[5] * wq[5]
              + tap[6] * wq[6] + tap[7] * wq[7] + tap[8] * wq[8];
    }
  }
#pragma unroll
  for (int j = 0; j < 9; j++) {
    int jj = half * 9 + j;
    off[((size_t)(b * 18 + jj) * HH + y) * WW + xi] = acc[j] + offb[jj];
  }
}

// ---------------------------------------------------------------------------
// Identity path: idt = bn3(1x1conv(x, id_w) + id_b), stored to ws
// thread = (b, og, y, x); computes 8 output channels
// ---------------------------------------------------------------------------
__global__ __launch_bounds__(256) void idconv_kernel(const float* __restrict__ x,
                                                     const float* __restrict__ idw,
                                                     const float* __restrict__ idb,
                                                     const float* __restrict__ g,
                                                     const float* __restrict__ bbias,
                                                     const float* __restrict__ mmean,
                                                     const float* __restrict__ vvar,
                                                     float* __restrict__ idt) {
  int t = blockIdx.x * 256 + threadIdx.x;  // total BB*16*HH*WW = 524288
  int xi = t & 127;
  int y = (t >> 7) & 127;
  int og = (t >> 14) & 15;
  int b = t >> 18;

  float acc[8];
#pragma unroll
  for (int i = 0; i < 8; i++) acc[i] = 0.f;

  const float* xp = x + (size_t)b * 64 * HWSZ + (size_t)y * WW + xi;
  for (int c = 0; c < 64; c++) {
    float xv = xp[(size_t)c * HWSZ];
#pragma unroll
    for (int i = 0; i < 8; i++) acc[i] += xv * idw[(og * 8 + i) * 64 + c];
  }
#pragma unroll
  for (int i = 0; i < 8; i++) {
    int o = og * 8 + i;
    float inv = g[o] / sqrtf(vvar[o] + 1e-5f);
    float beta = bbias[o] - mmean[o] * inv;
    idt[((size_t)(b * COUT + o) * HH + y) * WW + xi] = (acc[i] + idb[o]) * inv + beta;
  }
}

// ---------------------------------------------------------------------------
// Fused deformable conv as on-the-fly im2col GEMM.
// Block: 64 pixels (half a row) x 128 outputs, 256 threads.
// Phase 0: per (n, p) compute 4 bilinear taps (index into unpadded plane,
//          weight zeroed for pad taps) -> LDS.
// K-loop (chunks of 32): stage wT chunk (32x128) + sampled v chunk (32x64)
//          in LDS; each thread accumulates an 8x4 (o x p) register tile.
// Epilogue: BN (+ optional residual add) + ReLU.
// mode 0: out = relu(bn(acc))           (layer 1 -> h1)
// mode 1: out = relu(bn(acc) + idt)     (layer 2 -> d_out)
// ---------------------------------------------------------------------------
__global__ __launch_bounds__(256) void deform_gemm_kernel(
    const float* __restrict__ in, const float* __restrict__ off,
    const float* __restrict__ wT,
    const float* __restrict__ g, const float* __restrict__ bbias,
    const float* __restrict__ mmean, const float* __restrict__ vvar,
    const float* __restrict__ idt, float* __restrict__ out, int Cin, int mode) {
  __shared__ float swt[9][4][64];
  __shared__ int sidx[9][4][64];
  __shared__ float wlds[32][128];
  __shared__ float vlds[32][64];

  int tid = threadIdx.x;
  int pix0 = blockIdx.x * 64;
  int x0 = pix0 & 127;           // 0 or 64
  int y = (pix0 >> 7) & 127;
  int b = pix0 >> 14;

  // ---- Phase 0: sampling descriptors for 9 kernel points x 64 pixels ----
  for (int t = tid; t < 9 * 64; t += 256) {
    int n = t >> 6, p = t & 63;
    float offy = off[((size_t)(b * 18 + n) * HH + y) * WW + x0 + p];
    float offx = off[((size_t)(b * 18 + 9 + n) * HH + y) * WW + x0 + p];
    float py = offy + (float)(n / 3 - 1) + (float)(y + 1);
    float px = offx + (float)(n % 3 - 1) + (float)(x0 + p + 1);
    py = fminf(fmaxf(py, 0.f), 129.f);   // clip to [0, Hp-1], Hp = 130
    px = fminf(fmaxf(px, 0.f), 129.f);
    float fy = floorf(py), fx = floorf(px);
    float qy1 = fminf(fy + 1.f, 129.f), qx1 = fminf(fx + 1.f, 129.f);
    float ty0 = 1.f + (fy - py);     // (1 + (qy0 - py))
    float ty1 = 1.f - (qy1 - py);
    float tx0 = 1.f + (fx - px);
    float tx1 = 1.f - (qx1 - px);
    int iy0 = (int)fy - 1, ix0 = (int)fx - 1;     // into unpadded plane
    int iy1 = (int)qy1 - 1, ix1 = (int)qx1 - 1;
    bool vy0 = (unsigned)iy0 < (unsigned)HH, vx0 = (unsigned)ix0 < (unsigned)WW;
    bool vy1 = (unsigned)iy1 < (unsigned)HH, vx1 = (unsigned)ix1 < (unsigned)WW;
    // taps: lt(y0,x0), rb(y1,x1), lb(y0,x1), rt(y1,x0)
    swt[n][0][p] = (vy0 && vx0) ? ty0 * tx0 : 0.f;
    sidx[n][0][p] = (vy0 && vx0) ? iy0 * WW + ix0 : 0;
    swt[n][1][p] = (vy1 && vx1) ? ty1 * tx1 : 0.f;
    sidx[n][1][p] = (vy1 && vx1) ? iy1 * WW + ix1 : 0;
    swt[n][2][p] = (vy0 && vx1) ? ty0 * tx1 : 0.f;
    sidx[n][2][p] = (vy0 && vx1) ? iy0 * WW + ix1 : 0;
    swt[n][3][p] = (vy1 && vx0) ? ty1 * tx0 : 0.f;
    sidx[n][3][p] = (vy1 && vx0) ? iy1 * WW + ix0 : 0;
  }
  __syncthreads();

  float acc[8][4];
#pragma unroll
  for (int ii = 0; ii < 8; ii++)
#pragma unroll
    for (int jj = 0; jj < 4; jj++) acc[ii][jj] = 0.f;

  int ow = tid & 15, pw = tid >> 4;   // compute-phase tile coords
  int p = tid & 63, kb = tid >> 6;    // sampling-phase coords
  int K = Cin * 9;                    // 576 or 1152, both divisible by 32
  const float* inb = in + (size_t)b * Cin * HWSZ;

  for (int k0 = 0; k0 < K; k0 += 32) {
    // stage w chunk: 32 x 128 floats, coalesced float4 loads
#pragma unroll
    for (int i = 0; i < 4; i++) {
      int t4 = tid + i * 256;    // float4 index 0..1023
      int kk = t4 >> 5;          // 32 float4 per 128-wide row
      int c4 = t4 & 31;
      *(float4*)&wlds[kk][c4 * 4] =
          *(const float4*)&wT[(size_t)(k0 + kk) * COUT + c4 * 4];
    }
    // sample v chunk: 32 x 64 values
#pragma unroll
    for (int i = 0; i < 8; i++) {
      int kk = kb * 8 + i;
      int k = k0 + kk;
      int c = k / 9;
      int n = k - c * 9;
      const float* plane = inb + (size_t)c * HWSZ;
      float val = swt[n][0][p] * plane[sidx[n][0][p]]
                + swt[n][1][p] * plane[sidx[n][1][p]]
                + swt[n][2][p] * plane[sidx[n][2][p]]
                + swt[n][3][p] * plane[sidx[n][3][p]];
      vlds[kk][p] = val;
    }
    __syncthreads();

#pragma unroll
    for (int kk = 0; kk < 32; kk++) {
      float4 w0 = *(float4*)&wlds[kk][ow * 8];
      float4 w1 = *(float4*)&wlds[kk][ow * 8 + 4];
      float4 vv = *(float4*)&vlds[kk][pw * 4];
      float wv[8] = {w0.x, w0.y, w0.z, w0.w, w1.x, w1.y, w1.z, w1.w};
      float vl[4] = {vv.x, vv.y, vv.z, vv.w};
#pragma unroll
      for (int ii = 0; ii < 8; ii++)
#pragma unroll
        for (int jj = 0; jj < 4; jj++) acc[ii][jj] += wv[ii] * vl[jj];
    }
    __syncthreads();
  }

  // ---- Epilogue: BN (+ residual) + ReLU ----
#pragma unroll
  for (int ii = 0; ii < 8; ii++) {
    int o = ow * 8 + ii;
    float inv = g[o] / sqrtf(vvar[o] + 1e-5f);
    float beta = bbias[o] - mmean[o] * inv;
#pragma unroll
    for (int jj = 0; jj < 4; jj++) {
      int pp = pw * 4 + jj;
      size_t gidx = ((size_t)(b * COUT + o) * HH + y) * WW + x0 + pp;
      float r = acc[ii][jj] * inv + beta;
      if (mode == 1) r += idt[gidx];
      out[gidx] = fmaxf(r, 0.f);
    }
  }
}

// ---------------------------------------------------------------------------
extern "C" void kernel_launch(void* const* d_in, const int* in_sizes, int n_in,
                              void* d_out, int out_size, void* d_ws, size_t ws_size,
                              hipStream_t stream) {
  const float* x        = (const float*)d_in[0];
  const float* dc1_offw = (const float*)d_in[1];
  const float* dc1_offb = (const float*)d_in[2];
  const float* dc1_w    = (const float*)d_in[3];
  const float* bn1_g    = (const float*)d_in[4];
  const float* bn1_b    = (const float*)d_in[5];
  const float* bn1_m    = (const float*)d_in[6];
  const float* bn1_v    = (const float*)d_in[7];
  const float* dc2_offw = (const float*)d_in[8];
  const float* dc2_offb = (const float*)d_in[9];
  const float* dc2_w    = (const float*)d_in[10];
  const float* bn2_g    = (const float*)d_in[11];
  const float* bn2_b    = (const float*)d_in[12];
  const float* bn2_m    = (const float*)d_in[13];
  const float* bn2_v    = (const float*)d_in[14];
  const float* id_w     = (const float*)d_in[15];
  const float* id_b     = (const float*)d_in[16];
  const float* bn3_g    = (const float*)d_in[17];
  const float* bn3_b    = (const float*)d_in[18];
  const float* bn3_m    = (const float*)d_in[19];
  const float* bn3_v    = (const float*)d_in[20];

  float* ws = (float*)d_ws;
  float* off1 = ws;                                    // 2*18*128*128  = 589824
  float* off2 = off1 + (size_t)BB * 18 * HWSZ;         // 589824
  float* h1   = off2 + (size_t)BB * 18 * HWSZ;         // 2*128*128*128 = 4194304
  float* idt  = h1 + (size_t)BB * COUT * HWSZ;         // 4194304
  float* wT1  = idt + (size_t)BB * COUT * HWSZ;        // 576*128
  float* wT2  = wT1 + (size_t)576 * COUT;              // 1152*128

  const int K1 = 64 * 9, K2 = 128 * 9;

  hipLaunchKernelGGL(wtrans_kernel, dim3((K1 * COUT + 255) / 256), dim3(256), 0, stream,
                     dc1_w, wT1, K1);
  hipLaunchKernelGGL(wtrans_kernel, dim3((K2 * COUT + 255) / 256), dim3(256), 0, stream,
                     dc2_w, wT2, K2);
  // off1 = offset conv on x (Cin=64)
  hipLaunchKernelGGL(offconv_kernel, dim3(65536 / 256), dim3(256), 0, stream,
                     x, dc1_offw, dc1_offb, off1, 64);
  // h1 = relu(bn1(deform_conv1(x)))
  hipLaunchKernelGGL(deform_gemm_kernel, dim3(BB * HH * (WW / 64)), dim3(256), 0, stream,
                     x, off1, wT1, bn1_g, bn1_b, bn1_m, bn1_v, (const float*)nullptr,
                     h1, 64, 0);
  // idt = bn3(1x1 conv(x))
  hipLaunchKernelGGL(idconv_kernel, dim3(524288 / 256), dim3(256), 0, stream,
                     x, id_w, id_b, bn3_g, bn3_b, bn3_m, bn3_v, idt);
  // off2 = offset conv on h1 (Cin=128)
  hipLaunchKernelGGL(offconv_kernel, dim3(65536 / 256), dim3(256), 0, stream,
                     h1, dc2_offw, dc2_offb, off2, 128);
  // out = relu(bn2(deform_conv2(h1)) + idt)
  hipLaunchKernelGGL(deform_gemm_kernel, dim3(BB * HH * (WW / 64)), dim3(256), 0, stream,
                     h1, off2, wT2, bn2_g, bn2_b, bn2_m, bn2_v, idt,
                     (float*)d_out, 128, 1);
}

// Round 2
// 276.047 us; speedup vs baseline: 2.5132x; 2.5132x over previous
//
#include <hip/hip_runtime.h>
#include <math.h>

#define HH 128
#define WW 128
#define HWSZ (HH * WW)
#define BB 2
#define COUT 128

typedef __bf16 bf16x8 __attribute__((ext_vector_type(8)));
typedef float f32x4 __attribute__((ext_vector_type(4)));
typedef short s16x8 __attribute__((ext_vector_type(8)));
typedef short s16x4 __attribute__((ext_vector_type(4)));

// 4-byte-aligned float pair (bilinear x-pair load; may be unaligned to 8B)
struct __attribute__((aligned(4))) F2 { float x, y; };

__device__ __forceinline__ short tobf(float f) {
  union { float f; unsigned u; } v; v.f = f;
  unsigned r = v.u + 0x7fffu + ((v.u >> 16) & 1u);  // RNE
  return (short)(r >> 16);
}

// ---------------------------------------------------------------------------
// Weight prep: dst[o*dstStride + dstOff + col(k)] = bf16(src[o*K+k] * inv[o])
// col(k) = remapCin ? (k%9)*remapCin + (k/9) : k     (n-major K reorder)
// inv[o] = g[o]/sqrt(v[o]+eps) folds BN scale into the weights.
// ---------------------------------------------------------------------------
__global__ __launch_bounds__(256) void prep_scale_kernel(
    const float* __restrict__ src, const float* __restrict__ g,
    const float* __restrict__ v, short* __restrict__ dst,
    int K, int dstStride, int dstOff, int remapCin) {
  int k = blockIdx.x * 256 + threadIdx.x;
  int o = blockIdx.y;
  if (k >= K) return;
  float inv = g[o] / sqrtf(v[o] + 1e-5f);
  int col = remapCin ? (k % 9) * remapCin + (k / 9) : k;
  dst[(size_t)o * dstStride + dstOff + col] = tobf(src[(size_t)o * K + k] * inv);
}

// Offset-conv weights: rows 18..31 zero-padded (M padded to 32 for MFMA)
__global__ __launch_bounds__(256) void prep_off_kernel(const float* __restrict__ src,
                                                       short* __restrict__ dst,
                                                       int K, int Cin) {
  int k = blockIdx.x * 256 + threadIdx.x;
  int o = blockIdx.y;  // 0..31
  if (k >= K) return;
  int col = (k % 9) * Cin + (k / 9);
  dst[(size_t)o * K + col] = (o < 18) ? tobf(src[(size_t)o * K + k]) : (short)0;
}

// Epilogue constants: cb1 = beta1; cb2 = beta2 + id_b*inv3 + beta3
__global__ __launch_bounds__(128) void prep_bias_kernel(
    const float* b1, const float* m1, const float* g1, const float* v1,
    const float* b2, const float* m2, const float* g2, const float* v2,
    const float* b3, const float* m3, const float* g3, const float* v3,
    const float* idb, float* cb1, float* cb2) {
  int o = threadIdx.x;
  float inv1 = g1[o] / sqrtf(v1[o] + 1e-5f);
  float inv2 = g2[o] / sqrtf(v2[o] + 1e-5f);
  float inv3 = g3[o] / sqrtf(v3[o] + 1e-5f);
  cb1[o] = b1[o] - m1[o] * inv1;
  cb2[o] = (b2[o] - m2[o] * inv2) + idb[o] * inv3 + (b3[o] - m3[o] * inv3);
}

// ---------------------------------------------------------------------------
// Offset conv as MFMA GEMM: off[b,j,y,x] = conv3x3(in) + offb, j<18 (M pad 32)
// Block: 64 px x 32 M, 512 threads = 8 waves (wave = 16 px x 16 M).
// K is n-major: k' = n*Cin + c  ->  per 32-chunk, n (=ky*3+kx) is uniform.
// ---------------------------------------------------------------------------
__global__ __launch_bounds__(512, 4) void offconv_mfma_kernel(
    const float* __restrict__ in, const short* __restrict__ woff,
    const float* __restrict__ offb, float* __restrict__ off, int cshift) {
  __shared__ short wlds[32 * 40];
  __shared__ short vlds[64 * 40];
  const int tid = threadIdx.x;
  const int lane = tid & 63, wv = tid >> 6;
  const int pix0 = blockIdx.x * 64;
  const int x0 = pix0 & 127, y = (pix0 >> 7) & 127, b = pix0 >> 14;
  const int Cin = 1 << cshift;
  const int Kc = 9 << cshift;
  const float* inb = in + (size_t)b * Cin * HWSZ;
  const int p = lane, kb = wv;
  const int l15 = lane & 15, quad = lane >> 4;
  const int ptile = wv & 3, otile = wv >> 2;

  f32x4 acc = {0.f, 0.f, 0.f, 0.f};

  for (int k0 = 0; k0 < Kc; k0 += 32) {
    // stage weights (32 rows x 32 k): 128 slots of 8 bf16
    s16x8 wreg;
    if (tid < 128) wreg = *(const s16x8*)&woff[(size_t)(tid >> 2) * Kc + k0 + (tid & 3) * 8];
    // sample 4 regular-grid patch values (n uniform per chunk)
    int n = k0 >> cshift;
    int dy = n / 3 - 1, dx = n % 3 - 1;
    int yy = y + dy;
    int xx = x0 + p + dx;
    bool okx = ((unsigned)yy < (unsigned)HH) && ((unsigned)xx < (unsigned)WW);
    int c0 = (k0 & (Cin - 1)) + kb * 4;
    const float* pl = inb + (size_t)c0 * HWSZ + yy * WW + xx;
    s16x4 pk;
#pragma unroll
    for (int i = 0; i < 4; i++) {
      float vv = okx ? pl[(size_t)i * HWSZ] : 0.f;
      pk[i] = tobf(vv);
    }
    __syncthreads();
    if (tid < 128) *(s16x8*)&wlds[(tid >> 2) * 40 + (tid & 3) * 8] = wreg;
    *(s16x4*)&vlds[p * 40 + kb * 4] = pk;
    __syncthreads();
    bf16x8 bfr = *(const bf16x8*)&vlds[(ptile * 16 + l15) * 40 + quad * 8];
    bf16x8 afr = *(const bf16x8*)&wlds[(otile * 16 + l15) * 40 + quad * 8];
    acc = __builtin_amdgcn_mfma_f32_16x16x32_bf16(afr, bfr, acc, 0, 0, 0);
  }
#pragma unroll
  for (int r = 0; r < 4; r++) {
    int o = otile * 16 + quad * 4 + r;
    if (o < 18)
      off[(size_t)(b * 18 + o) * HWSZ + y * WW + x0 + ptile * 16 + l15] = acc[r] + offb[o];
  }
}

// ---------------------------------------------------------------------------
// Deformable conv as on-the-fly im2col MFMA GEMM, BN folded into weights,
// layer-2 identity residual folded in as 64 extra K columns (v = x directly).
// Block: 64 px x 128 out, 512 threads = 8 waves (wave = 16 px x 64 out).
// Descriptor per (n,p): 4 weights + 2 row-base offsets -> 2 float2 gathers.
// ---------------------------------------------------------------------------
__global__ __launch_bounds__(512, 4) void deform_mfma_kernel(
    const float* __restrict__ in, const float* __restrict__ off,
    const short* __restrict__ wbf, const float* __restrict__ cbv,
    const float* __restrict__ xid, float* __restrict__ out,
    int cshift, int KCONV, int KTOT) {
  __shared__ float4 dw4[576];
  __shared__ int2 dij[576];
  __shared__ short wlds[128 * 40];
  __shared__ short vlds[64 * 40];
  const int tid = threadIdx.x;
  const int lane = tid & 63, wv = tid >> 6;
  const int pix0 = blockIdx.x * 64;
  const int x0 = pix0 & 127, y = (pix0 >> 7) & 127, b = pix0 >> 14;
  const int Cin = 1 << cshift;
  const float* inb = in + (size_t)b * Cin * HWSZ;
  const int p = lane, kb = wv;
  const int l15 = lane & 15, quad = lane >> 4;
  const int ptile = wv & 3, ohalf = wv >> 2;

  // ---- bilinear descriptors: 9 kernel points x 64 pixels ----
  for (int t = tid; t < 576; t += 512) {
    int n = t >> 6, pp = t & 63;
    float offy = off[(size_t)(b * 18 + n) * HWSZ + y * WW + x0 + pp];
    float offx = off[(size_t)(b * 18 + 9 + n) * HWSZ + y * WW + x0 + pp];
    float py = offy + (float)(n / 3 - 1) + (float)(y + 1);
    float px = offx + (float)(n % 3 - 1) + (float)(x0 + pp + 1);
    py = fminf(fmaxf(py, 0.f), 129.f);
    px = fminf(fmaxf(px, 0.f), 129.f);
    float fy = floorf(py), fx = floorf(px);
    float qy1 = fminf(fy + 1.f, 129.f), qx1 = fminf(fx + 1.f, 129.f);
    float ty0 = 1.f + fy - py, ty1 = 1.f - (qy1 - py);
    float tx0 = 1.f + fx - px, tx1 = 1.f - (qx1 - px);
    int iy0 = (int)fy - 1, ix0 = (int)fx - 1;
    int iy1 = (int)qy1 - 1, ix1 = (int)qx1 - 1;
    if ((unsigned)iy0 >= (unsigned)HH) ty0 = 0.f;   // pad row -> weight 0
    if ((unsigned)iy1 >= (unsigned)HH) ty1 = 0.f;
    bool vx0 = (unsigned)ix0 < (unsigned)WW, vx1 = (unsigned)ix1 < (unsigned)WW;
    int bx = min(max(ix0, 0), WW - 2);
    float wxA = (((ix0 == bx) && vx0) ? tx0 : 0.f) + (((ix1 == bx) && vx1) ? tx1 : 0.f);
    float wxB = (((ix0 == bx + 1) && vx0) ? tx0 : 0.f) + (((ix1 == bx + 1) && vx1) ? tx1 : 0.f);
    dw4[t] = make_float4(ty0 * wxA, ty0 * wxB, ty1 * wxA, ty1 * wxB);
    int by0 = min(max(iy0, 0), HH - 1), by1 = min(max(iy1, 0), HH - 1);
    dij[t] = make_int2(by0 * WW + bx, by1 * WW + bx);
  }

  f32x4 acc[4];
#pragma unroll
  for (int i = 0; i < 4; i++) acc[i] = (f32x4){0.f, 0.f, 0.f, 0.f};
  __syncthreads();

  for (int k0 = 0; k0 < KTOT; k0 += 32) {
    // stage weights (128 rows x 32 k): 512 slots of 8 bf16
    s16x8 wreg = *(const s16x8*)&wbf[(size_t)(tid >> 2) * KTOT + k0 + (tid & 3) * 8];
    s16x4 pk;
    if (k0 < KCONV) {       // deformed samples; n uniform per chunk (n-major K)
      int n = k0 >> cshift;
      int c0 = (k0 & (Cin - 1)) + kb * 4;
      float4 w = dw4[n * 64 + p];
      int2 ij = dij[n * 64 + p];
      const float* pl = inb + (size_t)c0 * HWSZ;
#pragma unroll
      for (int i = 0; i < 4; i++) {
        const float* q = pl + (size_t)i * HWSZ;
        F2 a = *(const F2*)(q + ij.x);
        F2 c2 = *(const F2*)(q + ij.y);
        pk[i] = tobf(w.x * a.x + w.y * a.y + w.z * c2.x + w.w * c2.y);
      }
    } else {                // identity-residual columns: v = x directly
      int c0 = k0 - KCONV + kb * 4;
      const float* xb = xid + ((size_t)b * 64 + c0) * HWSZ + y * WW + x0 + p;
#pragma unroll
      for (int i = 0; i < 4; i++) pk[i] = tobf(xb[(size_t)i * HWSZ]);
    }
    __syncthreads();
    *(s16x8*)&wlds[(tid >> 2) * 40 + (tid & 3) * 8] = wreg;
    *(s16x4*)&vlds[p * 40 + kb * 4] = pk;
    __syncthreads();
    bf16x8 bfr = *(const bf16x8*)&vlds[(ptile * 16 + l15) * 40 + quad * 8];
#pragma unroll
    for (int ot = 0; ot < 4; ot++) {
      bf16x8 afr = *(const bf16x8*)&wlds[(ohalf * 64 + ot * 16 + l15) * 40 + quad * 8];
      acc[ot] = __builtin_amdgcn_mfma_f32_16x16x32_bf16(afr, bfr, acc[ot], 0, 0, 0);
    }
    __syncthreads();
  }

  // epilogue: + folded BN shift (and folded residual consts), ReLU
  int px_ = x0 + ptile * 16 + l15;
#pragma unroll
  for (int ot = 0; ot < 4; ot++) {
#pragma unroll
    for (int r = 0; r < 4; r++) {
      int o = ohalf * 64 + ot * 16 + quad * 4 + r;
      float v = acc[ot][r] + cbv[o];
      out[(size_t)(b * COUT + o) * HWSZ + y * WW + px_] = fmaxf(v, 0.f);
    }
  }
}

// ---------------------------------------------------------------------------
extern "C" void kernel_launch(void* const* d_in, const int* in_sizes, int n_in,
                              void* d_out, int out_size, void* d_ws, size_t ws_size,
                              hipStream_t stream) {
  const float* x        = (const float*)d_in[0];
  const float* dc1_offw = (const float*)d_in[1];
  const float* dc1_offb = (const float*)d_in[2];
  const float* dc1_w    = (const float*)d_in[3];
  const float* bn1_g    = (const float*)d_in[4];
  const float* bn1_b    = (const float*)d_in[5];
  const float* bn1_m    = (const float*)d_in[6];
  const float* bn1_v    = (const float*)d_in[7];
  const float* dc2_offw = (const float*)d_in[8];
  const float* dc2_offb = (const float*)d_in[9];
  const float* dc2_w    = (const float*)d_in[10];
  const float* bn2_g    = (const float*)d_in[11];
  const float* bn2_b    = (const float*)d_in[12];
  const float* bn2_m    = (const float*)d_in[13];
  const float* bn2_v    = (const float*)d_in[14];
  const float* id_w     = (const float*)d_in[15];
  const float* id_b     = (const float*)d_in[16];
  const float* bn3_g    = (const float*)d_in[17];
  const float* bn3_b    = (const float*)d_in[18];
  const float* bn3_m    = (const float*)d_in[19];
  const float* bn3_v    = (const float*)d_in[20];

  float* wsf = (float*)d_ws;
  float* off1 = wsf;                                   // 2*18*16384
  float* off2 = off1 + (size_t)BB * 18 * HWSZ;
  float* h1   = off2 + (size_t)BB * 18 * HWSZ;         // 2*128*16384
  float* cb1  = h1 + (size_t)BB * COUT * HWSZ;
  float* cb2  = cb1 + 128;
  short* wbf1  = (short*)(cb2 + 128);                  // 128 x 576
  short* wbf2  = wbf1 + (size_t)128 * 576;             // 128 x 1216
  short* woff1 = wbf2 + (size_t)128 * 1216;            // 32 x 576
  short* woff2 = woff1 + (size_t)32 * 576;             // 32 x 1152

  const int K1 = 576, K2 = 1152, KT2 = 1216;

  // --- weight / bias prep ---
  hipLaunchKernelGGL(prep_scale_kernel, dim3((K1 + 255) / 256, 128), dim3(256), 0, stream,
                     dc1_w, bn1_g, bn1_v, wbf1, K1, K1, 0, 64);
  hipLaunchKernelGGL(prep_scale_kernel, dim3((K2 + 255) / 256, 128), dim3(256), 0, stream,
                     dc2_w, bn2_g, bn2_v, wbf2, K2, KT2, 0, 128);
  hipLaunchKernelGGL(prep_scale_kernel, dim3(1, 128), dim3(256), 0, stream,
                     id_w, bn3_g, bn3_v, wbf2, 64, KT2, K2, 0);
  hipLaunchKernelGGL(prep_off_kernel, dim3((K1 + 255) / 256, 32), dim3(256), 0, stream,
                     dc1_offw, woff1, K1, 64);
  hipLaunchKernelGGL(prep_off_kernel, dim3((K2 + 255) / 256, 32), dim3(256), 0, stream,
                     dc2_offw, woff2, K2, 128);
  hipLaunchKernelGGL(prep_bias_kernel, dim3(1), dim3(128), 0, stream,
                     bn1_b, bn1_m, bn1_g, bn1_v, bn2_b, bn2_m, bn2_g, bn2_v,
                     bn3_b, bn3_m, bn3_g, bn3_v, id_b, cb1, cb2);

  // --- layer 1 ---
  hipLaunchKernelGGL(offconv_mfma_kernel, dim3(512), dim3(512), 0, stream,
                     x, woff1, dc1_offb, off1, 6);
  hipLaunchKernelGGL(deform_mfma_kernel, dim3(512), dim3(512), 0, stream,
                     x, off1, wbf1, cb1, (const float*)nullptr, h1, 6, K1, K1);
  // --- layer 2 (identity residual folded into GEMM) ---
  hipLaunchKernelGGL(offconv_mfma_kernel, dim3(512), dim3(512), 0, stream,
                     h1, woff2, dc2_offb, off2, 7);
  hipLaunchKernelGGL(deform_mfma_kernel, dim3(512), dim3(512), 0, stream,
                     h1, off2, wbf2, cb2, x, (float*)d_out, 7, K2, KT2);
}